// Round 2
// baseline (52.072 us; speedup 1.0000x reference)
//
#include <hip/hip_runtime.h>
#include <math.h>

#define L_BANDS 28
#define H 1024
#define W 1024
#define HW (H * W)

// 16-byte vector with only 8-byte alignment guarantee (X0 and dx are even ->
// element offsets are even -> 8B aligned; gfx950 handles align-8 dwordx4).
typedef float f4a8 __attribute__((ext_vector_type(4), aligned(8)));
typedef float f4a16 __attribute__((ext_vector_type(4), aligned(16)));
typedef float f4 __attribute__((ext_vector_type(4)));

// Gather formulation: out[Y,X] = sum_l mask[Y-dy_l, X-dx_l] * x[l, Y-dy_l, X-dx_l]
// Offsets mirror the reference's detached numpy math (float64, rint).
__global__ void cassi_fwd_gather4(const float* __restrict__ x,
                                  const float* __restrict__ mask,
                                  const float* __restrict__ phi_deg,
                                  const float* __restrict__ s_nom,
                                  float* __restrict__ out,
                                  int out_size) {
    __shared__ int s_dx[L_BANDS];
    __shared__ int s_dy[L_BANDS];
    __shared__ int s_Wp;
    __shared__ int s_dymax;

    if (threadIdx.x == 0) {
        double phi = (double)phi_deg[0] * 3.14159265358979323846 / 180.0;
        double c = cos(phi);
        double sn = sin(phi);
        double dxmin = 1e300, dymin = 1e300;
        for (int l = 0; l < L_BANDS; ++l) {
            double s = (double)s_nom[l];
            dxmin = fmin(dxmin, s * c);
            dymin = fmin(dymin, s * sn);
        }
        int dxmax = 0, dymax = 0;
        for (int l = 0; l < L_BANDS; ++l) {
            double s = (double)s_nom[l];
            int dx = (int)rint(s * c - dxmin);
            int dy = (int)rint(s * sn - dymin);
            s_dx[l] = dx;
            s_dy[l] = dy;
            dxmax = max(dxmax, dx);
            dymax = max(dymax, dy);
        }
        s_Wp = W + dxmax;
        s_dymax = dymax;
    }
    __syncthreads();

    const int Wp = s_Wp;
    const int dxmax = Wp - W;
    const int dymax = s_dymax;

    int tid = blockIdx.x * blockDim.x + threadIdx.x;
    int t0 = tid * 4;
    if (t0 >= out_size) return;

    int Y = t0 / Wp;
    int X0 = t0 - Y * Wp;

    // Interior: all 28 bands in-bounds for pixels X0..X0+3 -> no checks.
    if (Y >= dymax && Y <= H - 1 && X0 >= dxmax && X0 <= W - 4) {
        f4 acc = {0.f, 0.f, 0.f, 0.f};
#pragma unroll
        for (int l = 0; l < L_BANDS; ++l) {
            int p = (Y - s_dy[l]) * W + (X0 - s_dx[l]);
            f4 xv = *(const f4a8*)(x + l * HW + p);
            f4 mv = *(const f4a8*)(mask + p);
            acc += mv * xv;
        }
        *(f4a16*)(out + t0) = acc;  // t0 % 4 == 0 -> 16B aligned
    } else {
        // Edge path: per-pixel with bounds checks.
        for (int k = 0; k < 4; ++k) {
            int i = t0 + k;
            if (i >= out_size) break;
            int Yk = i / Wp;
            int Xk = i - Yk * Wp;
            float a = 0.0f;
#pragma unroll
            for (int l = 0; l < L_BANDS; ++l) {
                int h = Yk - s_dy[l];
                int w = Xk - s_dx[l];
                if ((unsigned)h < (unsigned)H && (unsigned)w < (unsigned)W) {
                    int p = h * W + w;
                    a = fmaf(mask[p], x[l * HW + p], a);
                }
            }
            out[i] = a;
        }
    }
}

extern "C" void kernel_launch(void* const* d_in, const int* in_sizes, int n_in,
                              void* d_out, int out_size, void* d_ws, size_t ws_size,
                              hipStream_t stream) {
    const float* x = (const float*)d_in[0];      // [1, 28, 1024, 1024]
    const float* mask = (const float*)d_in[1];   // [1024, 1024]
    const float* phi = (const float*)d_in[2];    // [1]
    const float* s_nom = (const float*)d_in[3];  // [28]
    float* out = (float*)d_out;                  // [1, Hp, Wp]

    const int threads = 256;
    const int tiles = (out_size + 3) / 4;
    const int blocks = (tiles + threads - 1) / threads;
    cassi_fwd_gather4<<<blocks, threads, 0, stream>>>(x, mask, phi, s_nom, out, out_size);
}

// Round 3
// 43.031 us; speedup vs baseline: 1.2101x; 1.2101x over previous
//
#include <hip/hip_runtime.h>
#include <math.h>

#define L_BANDS 28
#define H 1024
#define W 1024
#define HW (H * W)
#define HALF 14

// 8B vector, 4B-alignment-safe (Wp/dx parity is data-dependent in general).
typedef float f2 __attribute__((ext_vector_type(2), aligned(4)));

// Gather formulation: out[Y,X] = sum_l mask[Y-dy_l, X-dx_l] * x[l, Y-dy_l, X-dx_l]
// Offsets mirror the reference's detached numpy math (float64, rint).
// Latency-hiding strategy: per 2-px thread, issue 28 independent loads
// (14 bands x {x,mask}) into register arrays BEFORE any FMA, twice.
__global__ __launch_bounds__(256, 4)
void cassi_fwd_g2(const float* __restrict__ x,
                  const float* __restrict__ mask,
                  const float* __restrict__ phi_deg,
                  const float* __restrict__ s_nom,
                  float* __restrict__ out,
                  int out_size) {
    __shared__ int s_dx[L_BANDS];
    __shared__ int s_dy[L_BANDS];
    __shared__ int s_off[L_BANDS];  // dy*W + dx (gather offset in x/mask space)
    __shared__ int s_Wp;
    __shared__ int s_dymax;

    if (threadIdx.x == 0) {
        double phi = (double)phi_deg[0] * 3.14159265358979323846 / 180.0;
        double c = cos(phi);
        double sn = sin(phi);
        double dxmin = 1e300, dymin = 1e300;
        for (int l = 0; l < L_BANDS; ++l) {
            double s = (double)s_nom[l];
            dxmin = fmin(dxmin, s * c);
            dymin = fmin(dymin, s * sn);
        }
        int dxmax = 0, dymax = 0;
        for (int l = 0; l < L_BANDS; ++l) {
            double s = (double)s_nom[l];
            int dx = (int)rint(s * c - dxmin);
            int dy = (int)rint(s * sn - dymin);
            s_dx[l] = dx;
            s_dy[l] = dy;
            s_off[l] = dy * W + dx;
            dxmax = max(dxmax, dx);
            dymax = max(dymax, dy);
        }
        s_Wp = W + dxmax;
        s_dymax = dymax;
    }
    __syncthreads();

    const int Wp = s_Wp;
    const int dxmax = Wp - W;
    const int dymax = s_dymax;

    int t0 = (blockIdx.x * blockDim.x + threadIdx.x) * 2;
    if (t0 >= out_size) return;

    int Y = t0 / Wp;
    int X0 = t0 - Y * Wp;

    if (Y >= dymax && Y < H && X0 >= dxmax && X0 <= W - 2) {
        // Interior: all 28 bands in-bounds for both pixels -> no checks.
        const int pbase = Y * W + X0;
        f2 acc = {0.f, 0.f};
#pragma unroll
        for (int hh = 0; hh < 2; ++hh) {
            f2 xs[HALF], ms[HALF];
#pragma unroll
            for (int j = 0; j < HALF; ++j) {
                const int l = hh * HALF + j;
                const int p = pbase - s_off[l];
                xs[j] = *(const f2*)(x + l * HW + p);
                ms[j] = *(const f2*)(mask + p);
            }
#pragma unroll
            for (int j = 0; j < HALF; ++j) {
                acc += ms[j] * xs[j];
            }
        }
        *(f2*)(out + t0) = acc;  // t0 even -> 8B aligned (4B-safe type)
    } else {
        // Edge path: per-pixel with bounds checks.
        for (int k = 0; k < 2; ++k) {
            int i = t0 + k;
            if (i >= out_size) break;
            int Yk = i / Wp;
            int Xk = i - Yk * Wp;
            float a = 0.0f;
#pragma unroll
            for (int l = 0; l < L_BANDS; ++l) {
                int h = Yk - s_dy[l];
                int w = Xk - s_dx[l];
                if ((unsigned)h < (unsigned)H && (unsigned)w < (unsigned)W) {
                    int p = h * W + w;
                    a = fmaf(mask[p], x[l * HW + p], a);
                }
            }
            out[i] = a;
        }
    }
}

extern "C" void kernel_launch(void* const* d_in, const int* in_sizes, int n_in,
                              void* d_out, int out_size, void* d_ws, size_t ws_size,
                              hipStream_t stream) {
    const float* x = (const float*)d_in[0];      // [1, 28, 1024, 1024]
    const float* mask = (const float*)d_in[1];   // [1024, 1024]
    const float* phi = (const float*)d_in[2];    // [1]
    const float* s_nom = (const float*)d_in[3];  // [28]
    float* out = (float*)d_out;                  // [1, Hp, Wp]

    const int threads = 256;
    const int tiles = (out_size + 1) / 2;
    const int blocks = (tiles + threads - 1) / threads;
    cassi_fwd_g2<<<blocks, threads, 0, stream>>>(x, mask, phi, s_nom, out, out_size);
}